// Round 12
// baseline (393.187 us; speedup 1.0000x reference)
//
#include <hip/hip_runtime.h>

#define B_ 2
#define S_ 2048
#define D_ 1024
#define H_ 16
#define DH_ 64

typedef unsigned short u16;
typedef short v8s __attribute__((ext_vector_type(8)));
typedef float v4f __attribute__((ext_vector_type(4)));

__device__ __forceinline__ u16 f2bf(float x) {
    unsigned int u = __float_as_uint(x);
    u += 0x7fffu + ((u >> 16) & 1u);          // RNE
    return (u16)(u >> 16);
}
__device__ __forceinline__ float bf2f(u16 u) {
    return __uint_as_float(((unsigned int)u) << 16);
}

typedef __attribute__((address_space(1))) void gvoid;
typedef __attribute__((address_space(3))) void lvoid;
#define CP16(g, l) __builtin_amdgcn_global_load_lds((gvoid*)(g), (lvoid*)(l), 16, 0, 0)

// ---------------------------------------------------------------------------
// fused fp32 -> bf16 convert for all 9 tensors (grid.y = tensor id)
// ---------------------------------------------------------------------------
__global__ __launch_bounds__(256) void cvt9(
    const float* __restrict__ s0, const float* __restrict__ s1,
    const float* __restrict__ s2, const float* __restrict__ s3,
    const float* __restrict__ s4, const float* __restrict__ s5,
    const float* __restrict__ s6, const float* __restrict__ s7,
    const float* __restrict__ s8,
    u16* __restrict__ d0, u16* __restrict__ d1, u16* __restrict__ d2,
    u16* __restrict__ d3, u16* __restrict__ d4, u16* __restrict__ d5,
    u16* __restrict__ d6, u16* __restrict__ d7, u16* __restrict__ d8,
    int nbig, int nsmall)
{
    int y = blockIdx.y;
    const float* s = y==0?s0:y==1?s1:y==2?s2:y==3?s3:y==4?s4:y==5?s5:y==6?s6:y==7?s7:s8;
    u16* d = y==0?d0:y==1?d1:y==2?d2:y==3?d3:y==4?d4:y==5?d5:y==6?d6:y==7?d7:d8;
    int n4 = (y < 4) ? nbig : nsmall;
    int i = blockIdx.x * 256 + threadIdx.x;
    if (i < n4) {
        float4 v = ((const float4*)s)[i];
        ushort4 o;
        o.x = f2bf(v.x); o.y = f2bf(v.y); o.z = f2bf(v.z); o.w = f2bf(v.w);
        ((ushort4*)d)[i] = o;
    }
}

// ---------------------------------------------------------------------------
// Fused 4-projection bf16 GEMM (grid.z = projection). C = A @ W^T + bias.
// Round-12: DOUBLE-BUFFERED LDS (T3 minimum 2-phase). Old structure paid
// full load latency every K-iter: barrier -> CP16 -> barrier(vmcnt drain,
// nothing overlapping) -> compute. Now: prefetch tile k+1 into buf[cur^1]
// BEFORE computing tile k from buf[cur]; ONE __syncthreads per iter (its
// implicit vmcnt(0)+lgkmcnt(0) drain happens after the compute phase has
// covered most of the load latency). Buffer safety: readers of buf[cur^1]
// finished before the PREVIOUS iteration's barrier. Same kb order ->
// bit-identical accumulation. LDS 64KB -> 2 blocks/CU (latency hiding moved
// intra-block). BK=64 + XOR-swizzle retained (r7/r9 verified).
// proj 2 (V) writes per-head TRANSPOSED: VT[(b*16+h)*64+d][s].
// ---------------------------------------------------------------------------
__global__ __launch_bounds__(256, 2) void gemm_proj(
    const u16* __restrict__ A0, const u16* __restrict__ A1,
    const u16* __restrict__ A2, const u16* __restrict__ A3,
    const u16* __restrict__ W0, const u16* __restrict__ W1,
    const u16* __restrict__ W2, const u16* __restrict__ W3,
    const float* __restrict__ b0, const float* __restrict__ b1,
    const float* __restrict__ b2,
    u16* __restrict__ C0, u16* __restrict__ C1,
    u16* __restrict__ VT, u16* __restrict__ C3)
{
    const int K = D_, N = D_;
    const int proj = blockIdx.z;
    const u16* A = proj==0?A0:proj==1?A1:proj==2?A2:A3;
    const u16* W = proj==0?W0:proj==1?W1:proj==2?W2:W3;
    const float* bias = proj==0?b0:proj==1?b1:proj==2?b2:nullptr;

    __shared__ u16 As[2][128 * 64];
    __shared__ u16 Ws[2][128 * 64];
    const int tid  = threadIdx.x;
    const int wave = tid >> 6, lane = tid & 63;
    const int quad = lane >> 4, l15 = lane & 15;
    const int m0 = blockIdx.y * 128, n0 = blockIdx.x * 128;
    const int wr = wave >> 1, wc = wave & 1;

    const int lr8 = lane >> 3;               // 0..7 (row within 8-row segment)
    const int lc8 = ((lane & 7) ^ lr8) * 8;  // inverse-swizzled source col
    const int ksw = (l15 & 7) * 8;           // read-side XOR term

    v4f acc[4][4];
    #pragma unroll
    for (int i = 0; i < 4; ++i)
        #pragma unroll
        for (int j = 0; j < 4; ++j) acc[i][j] = (v4f){0.f, 0.f, 0.f, 0.f};

    auto stage = [&](int b, int kb) {
        #pragma unroll
        for (int c = 0; c < 4; ++c) {
            int seg = wave * 4 + c;          // 16 segments of 8 rows
            CP16(A + (size_t)(m0 + seg * 8 + lr8) * K + kb + lc8, &As[b][seg * 512]);
            CP16(W + (size_t)(n0 + seg * 8 + lr8) * K + kb + lc8, &Ws[b][seg * 512]);
        }
    };

    stage(0, 0);
    __syncthreads();                         // prologue drain

    for (int kb = 0; kb < K; kb += 64) {
        int cur = (kb >> 6) & 1;
        if (kb + 64 < K) stage(cur ^ 1, kb + 64);   // prefetch next tile
        #pragma unroll
        for (int kk = 0; kk < 2; ++kk) {
            v8s af[4], bf[4];
            #pragma unroll
            for (int i = 0; i < 4; ++i)
                af[i] = *(const v8s*)&As[cur][(wr * 64 + i * 16 + l15) * 64 + ((kk * 32 + quad * 8) ^ ksw)];
            #pragma unroll
            for (int j = 0; j < 4; ++j)
                bf[j] = *(const v8s*)&Ws[cur][(wc * 64 + j * 16 + l15) * 64 + ((kk * 32 + quad * 8) ^ ksw)];
            #pragma unroll
            for (int i = 0; i < 4; ++i)
                #pragma unroll
                for (int j = 0; j < 4; ++j)
                    acc[i][j] = __builtin_amdgcn_mfma_f32_16x16x32_bf16(af[i], bf[j], acc[i][j], 0, 0, 0);
        }
        __syncthreads();                     // drains prefetch; readers done
    }

    float bb[4];
    #pragma unroll
    for (int j = 0; j < 4; ++j)
        bb[j] = bias ? bias[n0 + wc * 64 + j * 16 + l15] : 0.f;

    if (proj == 2) {
        #pragma unroll
        for (int i = 0; i < 4; ++i)
            #pragma unroll
            for (int j = 0; j < 4; ++j) {
                int r0 = m0 + wr * 64 + i * 16 + quad * 4;       // s (global row)
                int c  = n0 + wc * 64 + j * 16 + l15;            // h*64+d
                ushort4 pw;
                pw.x = f2bf(acc[i][j][0] + bb[j]);
                pw.y = f2bf(acc[i][j][1] + bb[j]);
                pw.z = f2bf(acc[i][j][2] + bb[j]);
                pw.w = f2bf(acc[i][j][3] + bb[j]);
                size_t row_vt = (size_t)((r0 >> 11) * 16 + (c >> 6)) * 64 + (c & 63);
                *(ushort4*)&VT[row_vt * S_ + (r0 & 2047)] = pw;
            }
    } else {
        u16* C = proj == 0 ? C0 : proj == 1 ? C1 : C3;
        #pragma unroll
        for (int i = 0; i < 4; ++i)
            #pragma unroll
            for (int j = 0; j < 4; ++j)
                #pragma unroll
                for (int reg = 0; reg < 4; ++reg) {
                    int r = m0 + wr * 64 + i * 16 + quad * 4 + reg;
                    int c = n0 + wc * 64 + j * 16 + l15;
                    C[(size_t)r * N + c] = f2bf(acc[i][j][reg] + bb[j]);
                }
    }
}

// ---------------------------------------------------------------------------
// Output GEMM: fp32 out, 64x128 tile. Round-12: same 2-phase double-buffer
// transform (LDS 48KB -> 3 blocks/CU). BK=64 + XOR-swizzle retained.
// ---------------------------------------------------------------------------
__global__ __launch_bounds__(256, 2) void gemm_out(
    const u16* __restrict__ A, const u16* __restrict__ W,
    const float* __restrict__ bias, float* __restrict__ C)
{
    const int K = D_, N = D_;
    __shared__ u16 As[2][64 * 64];       // 16 KB
    __shared__ u16 Ws[2][128 * 64];      // 32 KB
    const int tid  = threadIdx.x;
    const int wave = tid >> 6, lane = tid & 63;
    const int quad = lane >> 4, l15 = lane & 15;
    const int m0 = blockIdx.y * 64, n0 = blockIdx.x * 128;
    const int wr = wave >> 1, wc = wave & 1;

    const int lr8 = lane >> 3;
    const int lc8 = ((lane & 7) ^ lr8) * 8;
    const int ksw = (l15 & 7) * 8;

    v4f acc[2][4];
    #pragma unroll
    for (int i = 0; i < 2; ++i)
        #pragma unroll
        for (int j = 0; j < 4; ++j) acc[i][j] = (v4f){0.f, 0.f, 0.f, 0.f};

    auto stage = [&](int b, int kb) {
        #pragma unroll
        for (int c = 0; c < 2; ++c) {
            int seg = wave * 2 + c;          // A: 8 segments of 8 rows
            CP16(A + (size_t)(m0 + seg * 8 + lr8) * K + kb + lc8, &As[b][seg * 512]);
        }
        #pragma unroll
        for (int c = 0; c < 4; ++c) {
            int seg = wave * 4 + c;          // W: 16 segments of 8 rows
            CP16(W + (size_t)(n0 + seg * 8 + lr8) * K + kb + lc8, &Ws[b][seg * 512]);
        }
    };

    stage(0, 0);
    __syncthreads();

    for (int kb = 0; kb < K; kb += 64) {
        int cur = (kb >> 6) & 1;
        if (kb + 64 < K) stage(cur ^ 1, kb + 64);
        #pragma unroll
        for (int kk = 0; kk < 2; ++kk) {
            v8s af[2], bf[4];
            #pragma unroll
            for (int i = 0; i < 2; ++i)
                af[i] = *(const v8s*)&As[cur][(wr * 32 + i * 16 + l15) * 64 + ((kk * 32 + quad * 8) ^ ksw)];
            #pragma unroll
            for (int j = 0; j < 4; ++j)
                bf[j] = *(const v8s*)&Ws[cur][(wc * 64 + j * 16 + l15) * 64 + ((kk * 32 + quad * 8) ^ ksw)];
            #pragma unroll
            for (int i = 0; i < 2; ++i)
                #pragma unroll
                for (int j = 0; j < 4; ++j)
                    acc[i][j] = __builtin_amdgcn_mfma_f32_16x16x32_bf16(af[i], bf[j], acc[i][j], 0, 0, 0);
        }
        __syncthreads();
    }

    #pragma unroll
    for (int i = 0; i < 2; ++i)
        #pragma unroll
        for (int j = 0; j < 4; ++j)
            #pragma unroll
            for (int reg = 0; reg < 4; ++reg) {
                int r = m0 + wr * 32 + i * 16 + quad * 4 + reg;
                int c = n0 + wc * 64 + j * 16 + l15;
                C[(size_t)r * N + c] = acc[i][j][reg] + bias[c];
            }
}

// ---------------------------------------------------------------------------
// MFMA flash relative attention, v16 — UNCHANGED from round 11 (verified
// 193.5us: v15 + T5 setprio around MFMA clusters).
// Structure: 1-deep PH pipeline, cooperative K/VT staging via global_load_lds
// (XOR-swizzled source, linear dest, XOR on read), single-plane PmT with
// write-time cndmask, PmT[80][20]/ps[16][72] (stride-40 rows = 10 banks),
// XCD-aware bh remap, waves_per_eu(4,4).
// ---------------------------------------------------------------------------
__global__ __launch_bounds__(256)
__attribute__((amdgpu_waves_per_eu(4, 4)))
void rel_attn16(
    const u16* __restrict__ QH, const u16* __restrict__ KH,
    const u16* __restrict__ VT, const u16* __restrict__ PH,
    const float* __restrict__ ub, const float* __restrict__ vb,
    u16* __restrict__ AO)
{
    __shared__ u16 Ks[64 * 64];         // k-tile, swizzled cols   (8 KB)
    __shared__ u16 VTs[64 * 64];        // vt-tile, swizzled cols  (8 KB)
    __shared__ u16 PmT[4][80][20];      // [wave][wcol][qrow]      (12.8 KB)
    __shared__ u16 ps[4][16][72];       // [wave][qrow][kcol]      (9.2 KB)

    const int tid  = threadIdx.x;
    const int wave = tid >> 6, lane = tid & 63;
    const int quad = lane >> 4, l15 = lane & 15;

    // XCD-aware remap: wg%8 selects XCD on MI355X -> each XCD serves 4 bh.
    const int wg  = blockIdx.x + 32 * blockIdx.y;
    const int xcd = wg & 7;
    const int i2  = wg >> 3;
    const int bh  = xcd + 8 * (i2 & 3);
    const int xt  = i2 >> 2;

    const int q0 = (xt * 4 + wave) * 16;
    const int bb = bh >> 4, h = bh & 15;
    const size_t base = (size_t)bb * S_ * D_ + (size_t)h * DH_;
    const size_t vtb  = (size_t)bh * DH_ * S_;

    // staging lane constants (K/VT): LDS[r][c] = global[r][c ^ (r&7)*8]
    const int lr8 = lane >> 3;
    const int lc8 = ((lane & 7) ^ lr8) * 8;
    const int ksw = (l15 & 7) * 8;

    // ---- Q fragments: qu = qh+u; qv rows +0 and +1 (in regs, 24 VGPRs) ----
    v8s quf[2], qvf0[2], qvf1[2];
    #pragma unroll
    for (int kc = 0; kc < 2; ++kc) {
        int r0 = q0 + l15;
        int r1 = min(r0 + 1, S_ - 1);
        v8s raw0 = *(const v8s*)&QH[base + (size_t)r0 * D_ + kc * 32 + quad * 8];
        v8s raw1 = *(const v8s*)&QH[base + (size_t)r1 * D_ + kc * 32 + quad * 8];
        #pragma unroll
        for (int j = 0; j < 8; ++j) {
            float ubj = ub[h * DH_ + kc * 32 + quad * 8 + j];
            float vbj = vb[h * DH_ + kc * 32 + quad * 8 + j];
            float f0 = bf2f((u16)raw0[j]);
            quf[kc][j]  = (short)f2bf(f0 + ubj);
            qvf0[kc][j] = (short)f2bf(f0 + vbj);
            qvf1[kc][j] = (short)f2bf(bf2f((u16)raw1[j]) + vbj);
        }
    }

    v4f o[4];
    float l_r[4];
    #pragma unroll
    for (int i = 0; i < 4; ++i) { o[i] = (v4f){0.f, 0.f, 0.f, 0.f}; l_r[i] = 0.f; }

    const int wb = l15 - quad * 4 + 15;   // wcol = ct*16 + wb - reg

    auto body = [&](int k0, const int phase) {
        // all waves finished reading the previous K/VT tile
        __syncthreads();

        // ---- cooperative stage of K and VT tiles (fire-and-forget DMA) ----
        #pragma unroll
        for (int c = 0; c < 2; ++c) {
            int seg = wave * 2 + c;
            CP16(KH + base + (size_t)(k0 + seg * 8 + lr8) * D_ + lc8, &Ks[seg * 512]);
            CP16(VT + vtb + (size_t)(seg * 8 + lr8) * S_ + k0 + lc8, &VTs[seg * 512]);
        }

        const int tmin = k0 - q0 - 15;
        const int jbase = (phase == 0) ? (S_ - 1 + tmin) : (tmin - 2);

        // PH fragment address for a given wcol-tile (phase folds at inline)
        auto phaddr = [&](int wcl) -> const u16* {
            int rw = wcl * 16 + l15;
            int j;
            if (phase == 1) {
                int t = tmin + rw;
                j = (t <= 0) ? (S_ - 1 + t) : max(t - 2, 0);
            } else {
                j = jbase + rw;
            }
            return &PH[base + (size_t)j * D_ + quad * 8];
        };

        // ---- pos pre-products: 1-deep pipelined PH loads + MFMA, one plane ----
        {
            const u16* ph0 = phaddr(0);
            v8s p0 = *(const v8s*)ph0;
            v8s p1 = *(const v8s*)(ph0 + 32);
            const bool doA = (tmin <= 0);
            #pragma unroll
            for (int wcl = 0; wcl < 5; ++wcl) {
                v8s n0, n1;
                if (wcl < 4) {                      // prefetch next tile's frags
                    const u16* phn = phaddr(wcl + 1);
                    n0 = *(const v8s*)phn;
                    n1 = *(const v8s*)(phn + 32);
                }
                int rw = wcl * 16 + l15;
                v4f sel;
                if (phase == 1) {
                    int t = tmin + rw;              // per-lane, shared by 4 regs
                    __builtin_amdgcn_s_setprio(1);
                    v4f a1 = (v4f){0.f, 0.f, 0.f, 0.f};
                    a1 = __builtin_amdgcn_mfma_f32_16x16x32_bf16(qvf1[0], p0, a1, 0, 0, 0);
                    a1 = __builtin_amdgcn_mfma_f32_16x16x32_bf16(qvf1[1], p1, a1, 0, 0, 0);
                    sel = a1;
                    if (doA) {
                        v4f a0 = (v4f){0.f, 0.f, 0.f, 0.f};
                        a0 = __builtin_amdgcn_mfma_f32_16x16x32_bf16(qvf0[0], p0, a0, 0, 0, 0);
                        a0 = __builtin_amdgcn_mfma_f32_16x16x32_bf16(qvf0[1], p1, a0, 0, 0, 0);
                        sel = (t >= 2) ? a1 : a0;   // per-lane cndmask
                    }
                    __builtin_amdgcn_s_setprio(0);
                } else {
                    const v8s a0s = (phase == 0) ? qvf0[0] : qvf1[0];
                    const v8s a1s = (phase == 0) ? qvf0[1] : qvf1[1];
                    __builtin_amdgcn_s_setprio(1);
                    v4f a = (v4f){0.f, 0.f, 0.f, 0.f};
                    a = __builtin_amdgcn_mfma_f32_16x16x32_bf16(a0s, p0, a, 0, 0, 0);
                    a = __builtin_amdgcn_mfma_f32_16x16x32_bf16(a1s, p1, a, 0, 0, 0);
                    __builtin_amdgcn_s_setprio(0);
                    sel = a;
                }
                ushort4 pw;
                pw.x = f2bf(sel[0]); pw.y = f2bf(sel[1]); pw.z = f2bf(sel[2]); pw.w = f2bf(sel[3]);
                *(ushort4*)&PmT[wave][rw][quad * 4] = pw;
                p0 = n0; p1 = n1;
            }
        }

        // staging complete & visible (syncthreads drains vmcnt+lgkmcnt)
        __syncthreads();

        // ---- content (K from LDS) + gather/exp per 16-col tile ----
        #pragma unroll
        for (int ct = 0; ct < 4; ++ct) {
            int kr = (ct * 16 + l15) * 64;
            v8s kbf0 = *(const v8s*)&Ks[kr + ((quad * 8) ^ ksw)];
            v8s kbf1 = *(const v8s*)&Ks[kr + ((32 + quad * 8) ^ ksw)];
            __builtin_amdgcn_s_setprio(1);
            v4f cs = (v4f){0.f, 0.f, 0.f, 0.f};
            cs = __builtin_amdgcn_mfma_f32_16x16x32_bf16(quf[0], kbf0, cs, 0, 0, 0);
            cs = __builtin_amdgcn_mfma_f32_16x16x32_bf16(quf[1], kbf1, cs, 0, 0, 0);
            __builtin_amdgcn_s_setprio(0);
            #pragma unroll
            for (int reg = 0; reg < 4; ++reg) {
                int qrow = quad * 4 + reg;
                int wcol = ct * 16 + wb - reg;
                float pos = bf2f(PmT[wave][wcol][qrow]);
                if (phase == 1) {
                    int t = tmin + wcol;
                    if (t == 1) pos = 0.f;
                }
                float e = __expf((cs[reg] + pos) * 0.03125f);
                ps[wave][qrow][ct * 16 + l15] = f2bf(e);
                l_r[reg] += e;
            }
        }

        // ---- PV (A-frags from ps, B-frags = VT from LDS) ----
        v8s af0 = *(const v8s*)&ps[wave][l15][quad * 8];
        v8s af1 = *(const v8s*)&ps[wave][l15][32 + quad * 8];
        __builtin_amdgcn_s_setprio(1);
        #pragma unroll
        for (int dt = 0; dt < 4; ++dt) {
            int vr = (dt * 16 + l15) * 64;
            v8s vbf0 = *(const v8s*)&VTs[vr + ((quad * 8) ^ ksw)];
            v8s vbf1 = *(const v8s*)&VTs[vr + ((32 + quad * 8) ^ ksw)];
            o[dt] = __builtin_amdgcn_mfma_f32_16x16x32_bf16(af0, vbf0, o[dt], 0, 0, 0);
            o[dt] = __builtin_amdgcn_mfma_f32_16x16x32_bf16(af1, vbf1, o[dt], 0, 0, 0);
        }
        __builtin_amdgcn_s_setprio(0);
    };

    // phase bounds: pure1 iff k0 <= q0-63; pure2 iff k0 >= q0+17
    const int k1end   = (q0 >= 63) ? ((((q0 - 63) >> 6) + 1) << 6) : 0;
    const int k2start = min((((q0 + 80) >> 6) << 6), S_);

    int k0 = 0;
    for (; k0 < k1end; k0 += 64)   body(k0, 0);
    for (; k0 < k2start; k0 += 64) body(k0, 1);
    for (; k0 < S_; k0 += 64)      body(k0, 2);

    // ---- row sums: in-quad shfl reduction (rows quad*4+reg live in this quad) ----
    #pragma unroll
    for (int reg = 0; reg < 4; ++reg) {
        float s = l_r[reg];
        #pragma unroll
        for (int off = 1; off < 16; off <<= 1)
            s += __shfl_xor(s, off, 16);
        l_r[reg] = 1.f / s;
    }
    #pragma unroll
    for (int dt = 0; dt < 4; ++dt)
        #pragma unroll
        for (int reg = 0; reg < 4; ++reg)
            AO[base + (size_t)(q0 + quad * 4 + reg) * D_ + dt * 16 + l15] =
                f2bf(o[dt][reg] * l_r[reg]);
}

extern "C" void kernel_launch(void* const* d_in, const int* in_sizes, int n_in,
                              void* d_out, int out_size, void* d_ws, size_t ws_size,
                              hipStream_t stream)
{
    (void)in_sizes; (void)n_in; (void)out_size; (void)ws_size;
    const float* q   = (const float*)d_in[0];
    const float* k   = (const float*)d_in[1];
    const float* v   = (const float*)d_in[2];
    const float* pe  = (const float*)d_in[3];
    const float* Wq  = (const float*)d_in[4];
    const float* bq  = (const float*)d_in[5];
    const float* Wk  = (const float*)d_in[6];
    const float* bk  = (const float*)d_in[7];
    const float* Wv  = (const float*)d_in[8];
    const float* bv  = (const float*)d_in[9];
    const float* Wp  = (const float*)d_in[10];
    const float* ub  = (const float*)d_in[11];
    const float* vbs = (const float*)d_in[12];
    const float* Wo  = (const float*)d_in[13];
    const float* bo  = (const float*)d_in[14];
    float* out = (float*)d_out;

    const size_t NSD = (size_t)B_ * S_ * D_;   // 4,194,304
    const size_t DD  = (size_t)D_ * D_;
    u16* ws = (u16*)d_ws;
    u16* qB  = ws;
    u16* kB  = qB + NSD;
    u16* vB  = kB + NSD;
    u16* pB  = vB + NSD;
    u16* WqB = pB + NSD;
    u16* WkB = WqB + DD;
    u16* WvB = WkB + DD;
    u16* WpB = WvB + DD;
    u16* WoB = WpB + DD;
    u16* QH  = WoB + DD;
    u16* KH  = QH + NSD;
    u16* VT  = KH + NSD;           // V projection written transposed
    u16* PHb = VT + NSD;
    u16* AO  = qB;                 // alias: qB dead after gemm_proj

    const int M = B_ * S_;         // 4096

    cvt9<<<dim3((int)(NSD / 4 / 256), 9), 256, 0, stream>>>(
        q, k, v, pe, Wq, Wk, Wv, Wp, Wo,
        qB, kB, vB, pB, WqB, WkB, WvB, WpB, WoB,
        (int)(NSD / 4), (int)(DD / 4));

    gemm_proj<<<dim3(D_ / 128, M / 128, 4), 256, 0, stream>>>(
        qB, kB, vB, pB, WqB, WkB, WvB, WpB, bq, bk, bv, QH, KH, VT, PHb);

    rel_attn16<<<dim3(S_ / 64, B_ * H_), 256, 0, stream>>>(QH, KH, VT, PHb, ub, vbs, AO);

    gemm_out<<<dim3(D_ / 128, M / 64), 256, 0, stream>>>(AO, WoB, bo, out);
}

// Round 13
// 382.876 us; speedup vs baseline: 1.0269x; 1.0269x over previous
//
#include <hip/hip_runtime.h>

#define B_ 2
#define S_ 2048
#define D_ 1024
#define H_ 16
#define DH_ 64

typedef unsigned short u16;
typedef short v8s __attribute__((ext_vector_type(8)));
typedef float v4f __attribute__((ext_vector_type(4)));

__device__ __forceinline__ u16 f2bf(float x) {
    unsigned int u = __float_as_uint(x);
    u += 0x7fffu + ((u >> 16) & 1u);          // RNE
    return (u16)(u >> 16);
}
__device__ __forceinline__ float bf2f(u16 u) {
    return __uint_as_float(((unsigned int)u) << 16);
}

typedef __attribute__((address_space(1))) void gvoid;
typedef __attribute__((address_space(3))) void lvoid;
#define CP16(g, l) __builtin_amdgcn_global_load_lds((gvoid*)(g), (lvoid*)(l), 16, 0, 0)

// ---------------------------------------------------------------------------
// fused fp32 -> bf16 convert for all 9 tensors (grid.y = tensor id).
// (r10 tested fusing activation converts into gemm_proj: regressed — the
// lockstep GEMM loop is latency-bound and reg-staging put vmcnt/lgkmcnt
// waits on the critical path. Standalone cvt9 is the verified best.)
// ---------------------------------------------------------------------------
__global__ __launch_bounds__(256) void cvt9(
    const float* __restrict__ s0, const float* __restrict__ s1,
    const float* __restrict__ s2, const float* __restrict__ s3,
    const float* __restrict__ s4, const float* __restrict__ s5,
    const float* __restrict__ s6, const float* __restrict__ s7,
    const float* __restrict__ s8,
    u16* __restrict__ d0, u16* __restrict__ d1, u16* __restrict__ d2,
    u16* __restrict__ d3, u16* __restrict__ d4, u16* __restrict__ d5,
    u16* __restrict__ d6, u16* __restrict__ d7, u16* __restrict__ d8,
    int nbig, int nsmall)
{
    int y = blockIdx.y;
    const float* s = y==0?s0:y==1?s1:y==2?s2:y==3?s3:y==4?s4:y==5?s5:y==6?s6:y==7?s7:s8;
    u16* d = y==0?d0:y==1?d1:y==2?d2:y==3?d3:y==4?d4:y==5?d5:y==6?d6:y==7?d7:d8;
    int n4 = (y < 4) ? nbig : nsmall;
    int i = blockIdx.x * 256 + threadIdx.x;
    if (i < n4) {
        float4 v = ((const float4*)s)[i];
        ushort4 o;
        o.x = f2bf(v.x); o.y = f2bf(v.y); o.z = f2bf(v.z); o.w = f2bf(v.w);
        ((ushort4*)d)[i] = o;
    }
}

// ---------------------------------------------------------------------------
// Fused 4-projection bf16 GEMM (grid.z = projection). C = A @ W^T + bias.
// BK=64 + XOR-swizzled LDS tiles, single-buffered CP16 DMA staging
// (round-9/11 verified best). r12 tested a 2-phase double-buffer: REGRESSED
// (64KB LDS halved resident blocks; cross-block overlap lost > intra-block
// pipelining gained — matches guide m99/m100/m132).
// proj 2 (V) writes per-head TRANSPOSED: VT[(b*16+h)*64+d][s].
// ---------------------------------------------------------------------------
__global__ __launch_bounds__(256, 3) void gemm_proj(
    const u16* __restrict__ A0, const u16* __restrict__ A1,
    const u16* __restrict__ A2, const u16* __restrict__ A3,
    const u16* __restrict__ W0, const u16* __restrict__ W1,
    const u16* __restrict__ W2, const u16* __restrict__ W3,
    const float* __restrict__ b0, const float* __restrict__ b1,
    const float* __restrict__ b2,
    u16* __restrict__ C0, u16* __restrict__ C1,
    u16* __restrict__ VT, u16* __restrict__ C3)
{
    const int K = D_, N = D_;
    const int proj = blockIdx.z;
    const u16* A = proj==0?A0:proj==1?A1:proj==2?A2:A3;
    const u16* W = proj==0?W0:proj==1?W1:proj==2?W2:W3;
    const float* bias = proj==0?b0:proj==1?b1:proj==2?b2:nullptr;

    __shared__ u16 As[128 * 64];
    __shared__ u16 Ws[128 * 64];
    const int tid  = threadIdx.x;
    const int wave = tid >> 6, lane = tid & 63;
    const int quad = lane >> 4, l15 = lane & 15;
    const int m0 = blockIdx.y * 128, n0 = blockIdx.x * 128;
    const int wr = wave >> 1, wc = wave & 1;

    const int lr8 = lane >> 3;               // 0..7 (row within 8-row segment)
    const int lc8 = ((lane & 7) ^ lr8) * 8;  // inverse-swizzled source col
    const int ksw = (l15 & 7) * 8;           // read-side XOR term

    v4f acc[4][4];
    #pragma unroll
    for (int i = 0; i < 4; ++i)
        #pragma unroll
        for (int j = 0; j < 4; ++j) acc[i][j] = (v4f){0.f, 0.f, 0.f, 0.f};

    for (int kb = 0; kb < K; kb += 64) {
        __syncthreads();
        #pragma unroll
        for (int c = 0; c < 4; ++c) {
            int seg = wave * 4 + c;          // 16 segments of 8 rows
            CP16(A + (size_t)(m0 + seg * 8 + lr8) * K + kb + lc8, &As[seg * 512]);
            CP16(W + (size_t)(n0 + seg * 8 + lr8) * K + kb + lc8, &Ws[seg * 512]);
        }
        __syncthreads();
        #pragma unroll
        for (int kk = 0; kk < 2; ++kk) {
            v8s af[4], bf[4];
            #pragma unroll
            for (int i = 0; i < 4; ++i)
                af[i] = *(const v8s*)&As[(wr * 64 + i * 16 + l15) * 64 + ((kk * 32 + quad * 8) ^ ksw)];
            #pragma unroll
            for (int j = 0; j < 4; ++j)
                bf[j] = *(const v8s*)&Ws[(wc * 64 + j * 16 + l15) * 64 + ((kk * 32 + quad * 8) ^ ksw)];
            #pragma unroll
            for (int i = 0; i < 4; ++i)
                #pragma unroll
                for (int j = 0; j < 4; ++j)
                    acc[i][j] = __builtin_amdgcn_mfma_f32_16x16x32_bf16(af[i], bf[j], acc[i][j], 0, 0, 0);
        }
    }

    float bb[4];
    #pragma unroll
    for (int j = 0; j < 4; ++j)
        bb[j] = bias ? bias[n0 + wc * 64 + j * 16 + l15] : 0.f;

    if (proj == 2) {
        #pragma unroll
        for (int i = 0; i < 4; ++i)
            #pragma unroll
            for (int j = 0; j < 4; ++j) {
                int r0 = m0 + wr * 64 + i * 16 + quad * 4;       // s (global row)
                int c  = n0 + wc * 64 + j * 16 + l15;            // h*64+d
                ushort4 pw;
                pw.x = f2bf(acc[i][j][0] + bb[j]);
                pw.y = f2bf(acc[i][j][1] + bb[j]);
                pw.z = f2bf(acc[i][j][2] + bb[j]);
                pw.w = f2bf(acc[i][j][3] + bb[j]);
                size_t row_vt = (size_t)((r0 >> 11) * 16 + (c >> 6)) * 64 + (c & 63);
                *(ushort4*)&VT[row_vt * S_ + (r0 & 2047)] = pw;
            }
    } else {
        u16* C = proj == 0 ? C0 : proj == 1 ? C1 : C3;
        #pragma unroll
        for (int i = 0; i < 4; ++i)
            #pragma unroll
            for (int j = 0; j < 4; ++j)
                #pragma unroll
                for (int reg = 0; reg < 4; ++reg) {
                    int r = m0 + wr * 64 + i * 16 + quad * 4 + reg;
                    int c = n0 + wc * 64 + j * 16 + l15;
                    C[(size_t)r * N + c] = f2bf(acc[i][j][reg] + bb[j]);
                }
    }
}

// ---------------------------------------------------------------------------
// Output GEMM: fp32 out, 64x128 tile. BK=64 + XOR-swizzle, single-buffered
// (round-9/11 verified best; r12 double-buffer regressed).
// ---------------------------------------------------------------------------
__global__ __launch_bounds__(256, 3) void gemm_out(
    const u16* __restrict__ A, const u16* __restrict__ W,
    const float* __restrict__ bias, float* __restrict__ C)
{
    const int K = D_, N = D_;
    __shared__ u16 As[64 * 64];          // 8 KB
    __shared__ u16 Ws[128 * 64];         // 16 KB
    const int tid  = threadIdx.x;
    const int wave = tid >> 6, lane = tid & 63;
    const int quad = lane >> 4, l15 = lane & 15;
    const int m0 = blockIdx.y * 64, n0 = blockIdx.x * 128;
    const int wr = wave >> 1, wc = wave & 1;

    const int lr8 = lane >> 3;
    const int lc8 = ((lane & 7) ^ lr8) * 8;
    const int ksw = (l15 & 7) * 8;

    v4f acc[2][4];
    #pragma unroll
    for (int i = 0; i < 2; ++i)
        #pragma unroll
        for (int j = 0; j < 4; ++j) acc[i][j] = (v4f){0.f, 0.f, 0.f, 0.f};

    for (int kb = 0; kb < K; kb += 64) {
        __syncthreads();
        #pragma unroll
        for (int c = 0; c < 2; ++c) {
            int seg = wave * 2 + c;          // A: 8 segments of 8 rows
            CP16(A + (size_t)(m0 + seg * 8 + lr8) * K + kb + lc8, &As[seg * 512]);
        }
        #pragma unroll
        for (int c = 0; c < 4; ++c) {
            int seg = wave * 4 + c;          // W: 16 segments of 8 rows
            CP16(W + (size_t)(n0 + seg * 8 + lr8) * K + kb + lc8, &Ws[seg * 512]);
        }
        __syncthreads();
        #pragma unroll
        for (int kk = 0; kk < 2; ++kk) {
            v8s af[2], bf[4];
            #pragma unroll
            for (int i = 0; i < 2; ++i)
                af[i] = *(const v8s*)&As[(wr * 32 + i * 16 + l15) * 64 + ((kk * 32 + quad * 8) ^ ksw)];
            #pragma unroll
            for (int j = 0; j < 4; ++j)
                bf[j] = *(const v8s*)&Ws[(wc * 64 + j * 16 + l15) * 64 + ((kk * 32 + quad * 8) ^ ksw)];
            #pragma unroll
            for (int i = 0; i < 2; ++i)
                #pragma unroll
                for (int j = 0; j < 4; ++j)
                    acc[i][j] = __builtin_amdgcn_mfma_f32_16x16x32_bf16(af[i], bf[j], acc[i][j], 0, 0, 0);
        }
    }

    #pragma unroll
    for (int i = 0; i < 2; ++i)
        #pragma unroll
        for (int j = 0; j < 4; ++j)
            #pragma unroll
            for (int reg = 0; reg < 4; ++reg) {
                int r = m0 + wr * 32 + i * 16 + quad * 4 + reg;
                int c = n0 + wc * 64 + j * 16 + l15;
                C[(size_t)r * N + c] = acc[i][j][reg] + bias[c];
            }
}

// ---------------------------------------------------------------------------
// MFMA flash relative attention, v16 — verified 193.5us (round 11).
// Session ladder: 398 (r0 baseline) -> 249 (cooperative K/VT LDS staging via
// global_load_lds, XCD-aware bh remap) -> 211 (single-plane PmT, 4 blk/CU)
// -> 197 (1-deep PH pipeline fits 64-VGPR tier, no spill) -> 193.5 (+T5
// setprio around MFMA clusters; 4 independent blocks/CU give the scheduler
// real arbitration choices — m191 regime).
// Structure: 1-deep PH pipeline, cooperative K/VT staging (XOR-swizzled
// source, linear dest, XOR on read), single-plane PmT with write-time
// cndmask, PmT[80][20]/ps[16][72] (stride-40 rows = 10 banks), XCD-aware
// bh remap, waves_per_eu(4,4).
// ---------------------------------------------------------------------------
__global__ __launch_bounds__(256)
__attribute__((amdgpu_waves_per_eu(4, 4)))
void rel_attn16(
    const u16* __restrict__ QH, const u16* __restrict__ KH,
    const u16* __restrict__ VT, const u16* __restrict__ PH,
    const float* __restrict__ ub, const float* __restrict__ vb,
    u16* __restrict__ AO)
{
    __shared__ u16 Ks[64 * 64];         // k-tile, swizzled cols   (8 KB)
    __shared__ u16 VTs[64 * 64];        // vt-tile, swizzled cols  (8 KB)
    __shared__ u16 PmT[4][80][20];      // [wave][wcol][qrow]      (12.8 KB)
    __shared__ u16 ps[4][16][72];       // [wave][qrow][kcol]      (9.2 KB)

    const int tid  = threadIdx.x;
    const int wave = tid >> 6, lane = tid & 63;
    const int quad = lane >> 4, l15 = lane & 15;

    // XCD-aware remap: wg%8 selects XCD on MI355X -> each XCD serves 4 bh.
    const int wg  = blockIdx.x + 32 * blockIdx.y;
    const int xcd = wg & 7;
    const int i2  = wg >> 3;
    const int bh  = xcd + 8 * (i2 & 3);
    const int xt  = i2 >> 2;

    const int q0 = (xt * 4 + wave) * 16;
    const int bb = bh >> 4, h = bh & 15;
    const size_t base = (size_t)bb * S_ * D_ + (size_t)h * DH_;
    const size_t vtb  = (size_t)bh * DH_ * S_;

    // staging lane constants (K/VT): LDS[r][c] = global[r][c ^ (r&7)*8]
    const int lr8 = lane >> 3;
    const int lc8 = ((lane & 7) ^ lr8) * 8;
    const int ksw = (l15 & 7) * 8;

    // ---- Q fragments: qu = qh+u; qv rows +0 and +1 (in regs, 24 VGPRs) ----
    v8s quf[2], qvf0[2], qvf1[2];
    #pragma unroll
    for (int kc = 0; kc < 2; ++kc) {
        int r0 = q0 + l15;
        int r1 = min(r0 + 1, S_ - 1);
        v8s raw0 = *(const v8s*)&QH[base + (size_t)r0 * D_ + kc * 32 + quad * 8];
        v8s raw1 = *(const v8s*)&QH[base + (size_t)r1 * D_ + kc * 32 + quad * 8];
        #pragma unroll
        for (int j = 0; j < 8; ++j) {
            float ubj = ub[h * DH_ + kc * 32 + quad * 8 + j];
            float vbj = vb[h * DH_ + kc * 32 + quad * 8 + j];
            float f0 = bf2f((u16)raw0[j]);
            quf[kc][j]  = (short)f2bf(f0 + ubj);
            qvf0[kc][j] = (short)f2bf(f0 + vbj);
            qvf1[kc][j] = (short)f2bf(bf2f((u16)raw1[j]) + vbj);
        }
    }

    v4f o[4];
    float l_r[4];
    #pragma unroll
    for (int i = 0; i < 4; ++i) { o[i] = (v4f){0.f, 0.f, 0.f, 0.f}; l_r[i] = 0.f; }

    const int wb = l15 - quad * 4 + 15;   // wcol = ct*16 + wb - reg

    auto body = [&](int k0, const int phase) {
        // all waves finished reading the previous K/VT tile
        __syncthreads();

        // ---- cooperative stage of K and VT tiles (fire-and-forget DMA) ----
        #pragma unroll
        for (int c = 0; c < 2; ++c) {
            int seg = wave * 2 + c;
            CP16(KH + base + (size_t)(k0 + seg * 8 + lr8) * D_ + lc8, &Ks[seg * 512]);
            CP16(VT + vtb + (size_t)(seg * 8 + lr8) * S_ + k0 + lc8, &VTs[seg * 512]);
        }

        const int tmin = k0 - q0 - 15;
        const int jbase = (phase == 0) ? (S_ - 1 + tmin) : (tmin - 2);

        // PH fragment address for a given wcol-tile (phase folds at inline)
        auto phaddr = [&](int wcl) -> const u16* {
            int rw = wcl * 16 + l15;
            int j;
            if (phase == 1) {
                int t = tmin + rw;
                j = (t <= 0) ? (S_ - 1 + t) : max(t - 2, 0);
            } else {
                j = jbase + rw;
            }
            return &PH[base + (size_t)j * D_ + quad * 8];
        };

        // ---- pos pre-products: 1-deep pipelined PH loads + MFMA, one plane ----
        {
            const u16* ph0 = phaddr(0);
            v8s p0 = *(const v8s*)ph0;
            v8s p1 = *(const v8s*)(ph0 + 32);
            const bool doA = (tmin <= 0);
            #pragma unroll
            for (int wcl = 0; wcl < 5; ++wcl) {
                v8s n0, n1;
                if (wcl < 4) {                      // prefetch next tile's frags
                    const u16* phn = phaddr(wcl + 1);
                    n0 = *(const v8s*)phn;
                    n1 = *(const v8s*)(phn + 32);
                }
                int rw = wcl * 16 + l15;
                v4f sel;
                if (phase == 1) {
                    int t = tmin + rw;              // per-lane, shared by 4 regs
                    __builtin_amdgcn_s_setprio(1);
                    v4f a1 = (v4f){0.f, 0.f, 0.f, 0.f};
                    a1 = __builtin_amdgcn_mfma_f32_16x16x32_bf16(qvf1[0], p0, a1, 0, 0, 0);
                    a1 = __builtin_amdgcn_mfma_f32_16x16x32_bf16(qvf1[1], p1, a1, 0, 0, 0);
                    sel = a1;
                    if (doA) {
                        v4f a0 = (v4f){0.f, 0.f, 0.f, 0.f};
                        a0 = __builtin_amdgcn_mfma_f32_16x16x32_bf16(qvf0[0], p0, a0, 0, 0, 0);
                        a0 = __builtin_amdgcn_mfma_f32_16x16x32_bf16(qvf0[1], p1, a0, 0, 0, 0);
                        sel = (t >= 2) ? a1 : a0;   // per-lane cndmask
                    }
                    __builtin_amdgcn_s_setprio(0);
                } else {
                    const v8s a0s = (phase == 0) ? qvf0[0] : qvf1[0];
                    const v8s a1s = (phase == 0) ? qvf0[1] : qvf1[1];
                    __builtin_amdgcn_s_setprio(1);
                    v4f a = (v4f){0.f, 0.f, 0.f, 0.f};
                    a = __builtin_amdgcn_mfma_f32_16x16x32_bf16(a0s, p0, a, 0, 0, 0);
                    a = __builtin_amdgcn_mfma_f32_16x16x32_bf16(a1s, p1, a, 0, 0, 0);
                    __builtin_amdgcn_s_setprio(0);
                    sel = a;
                }
                ushort4 pw;
                pw.x = f2bf(sel[0]); pw.y = f2bf(sel[1]); pw.z = f2bf(sel[2]); pw.w = f2bf(sel[3]);
                *(ushort4*)&PmT[wave][rw][quad * 4] = pw;
                p0 = n0; p1 = n1;
            }
        }

        // staging complete & visible (syncthreads drains vmcnt+lgkmcnt)
        __syncthreads();

        // ---- content (K from LDS) + gather/exp per 16-col tile ----
        #pragma unroll
        for (int ct = 0; ct < 4; ++ct) {
            int kr = (ct * 16 + l15) * 64;
            v8s kbf0 = *(const v8s*)&Ks[kr + ((quad * 8) ^ ksw)];
            v8s kbf1 = *(const v8s*)&Ks[kr + ((32 + quad * 8) ^ ksw)];
            __builtin_amdgcn_s_setprio(1);
            v4f cs = (v4f){0.f, 0.f, 0.f, 0.f};
            cs = __builtin_amdgcn_mfma_f32_16x16x32_bf16(quf[0], kbf0, cs, 0, 0, 0);
            cs = __builtin_amdgcn_mfma_f32_16x16x32_bf16(quf[1], kbf1, cs, 0, 0, 0);
            __builtin_amdgcn_s_setprio(0);
            #pragma unroll
            for (int reg = 0; reg < 4; ++reg) {
                int qrow = quad * 4 + reg;
                int wcol = ct * 16 + wb - reg;
                float pos = bf2f(PmT[wave][wcol][qrow]);
                if (phase == 1) {
                    int t = tmin + wcol;
                    if (t == 1) pos = 0.f;
                }
                float e = __expf((cs[reg] + pos) * 0.03125f);
                ps[wave][qrow][ct * 16 + l15] = f2bf(e);
                l_r[reg] += e;
            }
        }

        // ---- PV (A-frags from ps, B-frags = VT from LDS) ----
        v8s af0 = *(const v8s*)&ps[wave][l15][quad * 8];
        v8s af1 = *(const v8s*)&ps[wave][l15][32 + quad * 8];
        __builtin_amdgcn_s_setprio(1);
        #pragma unroll
        for (int dt = 0; dt < 4; ++dt) {
            int vr = (dt * 16 + l15) * 64;
            v8s vbf0 = *(const v8s*)&VTs[vr + ((quad * 8) ^ ksw)];
            v8s vbf1 = *(const v8s*)&VTs[vr + ((32 + quad * 8) ^ ksw)];
            o[dt] = __builtin_amdgcn_mfma_f32_16x16x32_bf16(af0, vbf0, o[dt], 0, 0, 0);
            o[dt] = __builtin_amdgcn_mfma_f32_16x16x32_bf16(af1, vbf1, o[dt], 0, 0, 0);
        }
        __builtin_amdgcn_s_setprio(0);
    };

    // phase bounds: pure1 iff k0 <= q0-63; pure2 iff k0 >= q0+17
    const int k1end   = (q0 >= 63) ? ((((q0 - 63) >> 6) + 1) << 6) : 0;
    const int k2start = min((((q0 + 80) >> 6) << 6), S_);

    int k0 = 0;
    for (; k0 < k1end; k0 += 64)   body(k0, 0);
    for (; k0 < k2start; k0 += 64) body(k0, 1);
    for (; k0 < S_; k0 += 64)      body(k0, 2);

    // ---- row sums: in-quad shfl reduction (rows quad*4+reg live in this quad) ----
    #pragma unroll
    for (int reg = 0; reg < 4; ++reg) {
        float s = l_r[reg];
        #pragma unroll
        for (int off = 1; off < 16; off <<= 1)
            s += __shfl_xor(s, off, 16);
        l_r[reg] = 1.f / s;
    }
    #pragma unroll
    for (int dt = 0; dt < 4; ++dt)
        #pragma unroll
        for (int reg = 0; reg < 4; ++reg)
            AO[base + (size_t)(q0 + quad * 4 + reg) * D_ + dt * 16 + l15] =
                f2bf(o[dt][reg] * l_r[reg]);
}

extern "C" void kernel_launch(void* const* d_in, const int* in_sizes, int n_in,
                              void* d_out, int out_size, void* d_ws, size_t ws_size,
                              hipStream_t stream)
{
    (void)in_sizes; (void)n_in; (void)out_size; (void)ws_size;
    const float* q   = (const float*)d_in[0];
    const float* k   = (const float*)d_in[1];
    const float* v   = (const float*)d_in[2];
    const float* pe  = (const float*)d_in[3];
    const float* Wq  = (const float*)d_in[4];
    const float* bq  = (const float*)d_in[5];
    const float* Wk  = (const float*)d_in[6];
    const float* bk  = (const float*)d_in[7];
    const float* Wv  = (const float*)d_in[8];
    const float* bv  = (const float*)d_in[9];
    const float* Wp  = (const float*)d_in[10];
    const float* ub  = (const float*)d_in[11];
    const float* vbs = (const float*)d_in[12];
    const float* Wo  = (const float*)d_in[13];
    const float* bo  = (const float*)d_in[14];
    float* out = (float*)d_out;

    const size_t NSD = (size_t)B_ * S_ * D_;   // 4,194,304
    const size_t DD  = (size_t)D_ * D_;
    u16* ws = (u16*)d_ws;
    u16* qB  = ws;
    u16* kB  = qB + NSD;
    u16* vB  = kB + NSD;
    u16* pB  = vB + NSD;
    u16* WqB = pB + NSD;
    u16* WkB = WqB + DD;
    u16* WvB = WkB + DD;
    u16* WpB = WvB + DD;
    u16* WoB = WpB + DD;
    u16* QH  = WoB + DD;
    u16* KH  = QH + NSD;
    u16* VT  = KH + NSD;           // V projection written transposed
    u16* PHb = VT + NSD;
    u16* AO  = qB;                 // alias: qB dead after gemm_proj

    const int M = B_ * S_;         // 4096

    cvt9<<<dim3((int)(NSD / 4 / 256), 9), 256, 0, stream>>>(
        q, k, v, pe, Wq, Wk, Wv, Wp, Wo,
        qB, kB, vB, pB, WqB, WkB, WvB, WpB, WoB,
        (int)(NSD / 4), (int)(DD / 4));

    gemm_proj<<<dim3(D_ / 128, M / 128, 4), 256, 0, stream>>>(
        qB, kB, vB, pB, WqB, WkB, WvB, WpB, bq, bk, bv, QH, KH, VT, PHb);

    rel_attn16<<<dim3(S_ / 64, B_ * H_), 256, 0, stream>>>(QH, KH, VT, PHb, ub, vbs, AO);

    gemm_out<<<dim3(D_ / 128, M / 64), 256, 0, stream>>>(AO, WoB, bo, out);
}

// Round 14
// 367.722 us; speedup vs baseline: 1.0693x; 1.0412x over previous
//
#include <hip/hip_runtime.h>

#define B_ 2
#define S_ 2048
#define D_ 1024
#define H_ 16
#define DH_ 64

typedef unsigned short u16;
typedef short v8s __attribute__((ext_vector_type(8)));
typedef float v4f __attribute__((ext_vector_type(4)));

__device__ __forceinline__ u16 f2bf(float x) {
    unsigned int u = __float_as_uint(x);
    u += 0x7fffu + ((u >> 16) & 1u);          // RNE
    return (u16)(u >> 16);
}
__device__ __forceinline__ float bf2f(u16 u) {
    return __uint_as_float(((unsigned int)u) << 16);
}

typedef __attribute__((address_space(1))) void gvoid;
typedef __attribute__((address_space(3))) void lvoid;
#define CP16(g, l) __builtin_amdgcn_global_load_lds((gvoid*)(g), (lvoid*)(l), 16, 0, 0)

// ---------------------------------------------------------------------------
// fused fp32 -> bf16 convert for all 9 tensors (grid.y = tensor id).
// ---------------------------------------------------------------------------
__global__ __launch_bounds__(256) void cvt9(
    const float* __restrict__ s0, const float* __restrict__ s1,
    const float* __restrict__ s2, const float* __restrict__ s3,
    const float* __restrict__ s4, const float* __restrict__ s5,
    const float* __restrict__ s6, const float* __restrict__ s7,
    const float* __restrict__ s8,
    u16* __restrict__ d0, u16* __restrict__ d1, u16* __restrict__ d2,
    u16* __restrict__ d3, u16* __restrict__ d4, u16* __restrict__ d5,
    u16* __restrict__ d6, u16* __restrict__ d7, u16* __restrict__ d8,
    int nbig, int nsmall)
{
    int y = blockIdx.y;
    const float* s = y==0?s0:y==1?s1:y==2?s2:y==3?s3:y==4?s4:y==5?s5:y==6?s6:y==7?s7:s8;
    u16* d = y==0?d0:y==1?d1:y==2?d2:y==3?d3:y==4?d4:y==5?d5:y==6?d6:y==7?d7:d8;
    int n4 = (y < 4) ? nbig : nsmall;
    int i = blockIdx.x * 256 + threadIdx.x;
    if (i < n4) {
        float4 v = ((const float4*)s)[i];
        ushort4 o;
        o.x = f2bf(v.x); o.y = f2bf(v.y); o.z = f2bf(v.z); o.w = f2bf(v.w);
        ((ushort4*)d)[i] = o;
    }
}

// ---------------------------------------------------------------------------
// Fused 4-projection bf16 GEMM. C = A @ W^T + bias.
// BK=64 + XOR-swizzled LDS tiles, single-buffered CP16 DMA (r9/r11 best).
// Round-14: T1 XCD-aware block swizzle. Default round-robin scatters each
// XCD's ~128 concurrent blocks over all 4 projs x 32 row-panels (~40MB
// working set >> 4MB L2). Remap wg' = (wg&7)*128 + wg>>3 (bijective,
// nwg=1024) so each XCD serves one contiguous half-projection: A-panels
// reused by 8 n-blocks, W by 16 y-blocks (~6MB working set). The staging
// loop is latency-bound (r10/r12 A/B), so L3/HBM misses -> L2 hits cut the
// exposed latency directly. Pure tile permutation -> bit-identical.
// proj 2 (V) writes per-head TRANSPOSED: VT[(b*16+h)*64+d][s].
// ---------------------------------------------------------------------------
__global__ __launch_bounds__(256, 3) void gemm_proj(
    const u16* __restrict__ A0, const u16* __restrict__ A1,
    const u16* __restrict__ A2, const u16* __restrict__ A3,
    const u16* __restrict__ W0, const u16* __restrict__ W1,
    const u16* __restrict__ W2, const u16* __restrict__ W3,
    const float* __restrict__ b0, const float* __restrict__ b1,
    const float* __restrict__ b2,
    u16* __restrict__ C0, u16* __restrict__ C1,
    u16* __restrict__ VT, u16* __restrict__ C3)
{
    const int K = D_, N = D_;
    // XCD-aware remap (see header comment)
    const int wg  = blockIdx.x + 8 * blockIdx.y + 256 * blockIdx.z;  // 0..1023
    const int wgp = (wg & 7) * 128 + (wg >> 3);
    const int proj = wgp >> 8;
    const int m0 = ((wgp >> 3) & 31) * 128;
    const int n0 = (wgp & 7) * 128;

    const u16* A = proj==0?A0:proj==1?A1:proj==2?A2:A3;
    const u16* W = proj==0?W0:proj==1?W1:proj==2?W2:W3;
    const float* bias = proj==0?b0:proj==1?b1:proj==2?b2:nullptr;

    __shared__ u16 As[128 * 64];
    __shared__ u16 Ws[128 * 64];
    const int tid  = threadIdx.x;
    const int wave = tid >> 6, lane = tid & 63;
    const int quad = lane >> 4, l15 = lane & 15;
    const int wr = wave >> 1, wc = wave & 1;

    const int lr8 = lane >> 3;               // 0..7 (row within 8-row segment)
    const int lc8 = ((lane & 7) ^ lr8) * 8;  // inverse-swizzled source col
    const int ksw = (l15 & 7) * 8;           // read-side XOR term

    v4f acc[4][4];
    #pragma unroll
    for (int i = 0; i < 4; ++i)
        #pragma unroll
        for (int j = 0; j < 4; ++j) acc[i][j] = (v4f){0.f, 0.f, 0.f, 0.f};

    for (int kb = 0; kb < K; kb += 64) {
        __syncthreads();
        #pragma unroll
        for (int c = 0; c < 4; ++c) {
            int seg = wave * 4 + c;          // 16 segments of 8 rows
            CP16(A + (size_t)(m0 + seg * 8 + lr8) * K + kb + lc8, &As[seg * 512]);
            CP16(W + (size_t)(n0 + seg * 8 + lr8) * K + kb + lc8, &Ws[seg * 512]);
        }
        __syncthreads();
        #pragma unroll
        for (int kk = 0; kk < 2; ++kk) {
            v8s af[4], bf[4];
            #pragma unroll
            for (int i = 0; i < 4; ++i)
                af[i] = *(const v8s*)&As[(wr * 64 + i * 16 + l15) * 64 + ((kk * 32 + quad * 8) ^ ksw)];
            #pragma unroll
            for (int j = 0; j < 4; ++j)
                bf[j] = *(const v8s*)&Ws[(wc * 64 + j * 16 + l15) * 64 + ((kk * 32 + quad * 8) ^ ksw)];
            #pragma unroll
            for (int i = 0; i < 4; ++i)
                #pragma unroll
                for (int j = 0; j < 4; ++j)
                    acc[i][j] = __builtin_amdgcn_mfma_f32_16x16x32_bf16(af[i], bf[j], acc[i][j], 0, 0, 0);
        }
    }

    float bb[4];
    #pragma unroll
    for (int j = 0; j < 4; ++j)
        bb[j] = bias ? bias[n0 + wc * 64 + j * 16 + l15] : 0.f;

    if (proj == 2) {
        #pragma unroll
        for (int i = 0; i < 4; ++i)
            #pragma unroll
            for (int j = 0; j < 4; ++j) {
                int r0 = m0 + wr * 64 + i * 16 + quad * 4;       // s (global row)
                int c  = n0 + wc * 64 + j * 16 + l15;            // h*64+d
                ushort4 pw;
                pw.x = f2bf(acc[i][j][0] + bb[j]);
                pw.y = f2bf(acc[i][j][1] + bb[j]);
                pw.z = f2bf(acc[i][j][2] + bb[j]);
                pw.w = f2bf(acc[i][j][3] + bb[j]);
                size_t row_vt = (size_t)((r0 >> 11) * 16 + (c >> 6)) * 64 + (c & 63);
                *(ushort4*)&VT[row_vt * S_ + (r0 & 2047)] = pw;
            }
    } else {
        u16* C = proj == 0 ? C0 : proj == 1 ? C1 : C3;
        #pragma unroll
        for (int i = 0; i < 4; ++i)
            #pragma unroll
            for (int j = 0; j < 4; ++j)
                #pragma unroll
                for (int reg = 0; reg < 4; ++reg) {
                    int r = m0 + wr * 64 + i * 16 + quad * 4 + reg;
                    int c = n0 + wc * 64 + j * 16 + l15;
                    C[(size_t)r * N + c] = f2bf(acc[i][j][reg] + bb[j]);
                }
    }
}

// ---------------------------------------------------------------------------
// Output GEMM: fp32 out, 64x128 tile. BK=64 + XOR-swizzle, single-buffered.
// Round-14: same T1 XCD swizzle (512 blocks; wg' = (wg&7)*64 + wg>>3 ->
// per-XCD working set A 1MB + W 2MB < 4MB L2).
// ---------------------------------------------------------------------------
__global__ __launch_bounds__(256, 3) void gemm_out(
    const u16* __restrict__ A, const u16* __restrict__ W,
    const float* __restrict__ bias, float* __restrict__ C)
{
    const int K = D_, N = D_;
    const int wg  = blockIdx.x + 8 * blockIdx.y;       // 0..511
    const int wgp = (wg & 7) * 64 + (wg >> 3);
    const int m0 = (wgp >> 3) * 64;
    const int n0 = (wgp & 7) * 128;

    __shared__ u16 As[64 * 64];          // 8 KB
    __shared__ u16 Ws[128 * 64];         // 16 KB
    const int tid  = threadIdx.x;
    const int wave = tid >> 6, lane = tid & 63;
    const int quad = lane >> 4, l15 = lane & 15;
    const int wr = wave >> 1, wc = wave & 1;

    const int lr8 = lane >> 3;
    const int lc8 = ((lane & 7) ^ lr8) * 8;
    const int ksw = (l15 & 7) * 8;

    v4f acc[2][4];
    #pragma unroll
    for (int i = 0; i < 2; ++i)
        #pragma unroll
        for (int j = 0; j < 4; ++j) acc[i][j] = (v4f){0.f, 0.f, 0.f, 0.f};

    for (int kb = 0; kb < K; kb += 64) {
        __syncthreads();
        #pragma unroll
        for (int c = 0; c < 2; ++c) {
            int seg = wave * 2 + c;          // A: 8 segments of 8 rows
            CP16(A + (size_t)(m0 + seg * 8 + lr8) * K + kb + lc8, &As[seg * 512]);
        }
        #pragma unroll
        for (int c = 0; c < 4; ++c) {
            int seg = wave * 4 + c;          // W: 16 segments of 8 rows
            CP16(W + (size_t)(n0 + seg * 8 + lr8) * K + kb + lc8, &Ws[seg * 512]);
        }
        __syncthreads();
        #pragma unroll
        for (int kk = 0; kk < 2; ++kk) {
            v8s af[2], bf[4];
            #pragma unroll
            for (int i = 0; i < 2; ++i)
                af[i] = *(const v8s*)&As[(wr * 32 + i * 16 + l15) * 64 + ((kk * 32 + quad * 8) ^ ksw)];
            #pragma unroll
            for (int j = 0; j < 4; ++j)
                bf[j] = *(const v8s*)&Ws[(wc * 64 + j * 16 + l15) * 64 + ((kk * 32 + quad * 8) ^ ksw)];
            #pragma unroll
            for (int i = 0; i < 2; ++i)
                #pragma unroll
                for (int j = 0; j < 4; ++j)
                    acc[i][j] = __builtin_amdgcn_mfma_f32_16x16x32_bf16(af[i], bf[j], acc[i][j], 0, 0, 0);
        }
    }

    #pragma unroll
    for (int i = 0; i < 2; ++i)
        #pragma unroll
        for (int j = 0; j < 4; ++j)
            #pragma unroll
            for (int reg = 0; reg < 4; ++reg) {
                int r = m0 + wr * 32 + i * 16 + quad * 4 + reg;
                int c = n0 + wc * 64 + j * 16 + l15;
                C[(size_t)r * N + c] = acc[i][j][reg] + bias[c];
            }
}

// ---------------------------------------------------------------------------
// MFMA flash relative attention, v16 — verified 193.5us (rounds 11/13).
// Structure: 1-deep PH pipeline, cooperative K/VT staging (XOR-swizzled
// source, linear dest, XOR on read), single-plane PmT with write-time
// cndmask, PmT[80][20]/ps[16][72] (stride-40 rows = 10 banks), XCD-aware
// bh remap, waves_per_eu(4,4), T5 setprio around MFMA clusters.
// ---------------------------------------------------------------------------
__global__ __launch_bounds__(256)
__attribute__((amdgpu_waves_per_eu(4, 4)))
void rel_attn16(
    const u16* __restrict__ QH, const u16* __restrict__ KH,
    const u16* __restrict__ VT, const u16* __restrict__ PH,
    const float* __restrict__ ub, const float* __restrict__ vb,
    u16* __restrict__ AO)
{
    __shared__ u16 Ks[64 * 64];         // k-tile, swizzled cols   (8 KB)
    __shared__ u16 VTs[64 * 64];        // vt-tile, swizzled cols  (8 KB)
    __shared__ u16 PmT[4][80][20];      // [wave][wcol][qrow]      (12.8 KB)
    __shared__ u16 ps[4][16][72];       // [wave][qrow][kcol]      (9.2 KB)

    const int tid  = threadIdx.x;
    const int wave = tid >> 6, lane = tid & 63;
    const int quad = lane >> 4, l15 = lane & 15;

    // XCD-aware remap: wg%8 selects XCD on MI355X -> each XCD serves 4 bh.
    const int wg  = blockIdx.x + 32 * blockIdx.y;
    const int xcd = wg & 7;
    const int i2  = wg >> 3;
    const int bh  = xcd + 8 * (i2 & 3);
    const int xt  = i2 >> 2;

    const int q0 = (xt * 4 + wave) * 16;
    const int bb = bh >> 4, h = bh & 15;
    const size_t base = (size_t)bb * S_ * D_ + (size_t)h * DH_;
    const size_t vtb  = (size_t)bh * DH_ * S_;

    // staging lane constants (K/VT): LDS[r][c] = global[r][c ^ (r&7)*8]
    const int lr8 = lane >> 3;
    const int lc8 = ((lane & 7) ^ lr8) * 8;
    const int ksw = (l15 & 7) * 8;

    // ---- Q fragments: qu = qh+u; qv rows +0 and +1 (in regs, 24 VGPRs) ----
    v8s quf[2], qvf0[2], qvf1[2];
    #pragma unroll
    for (int kc = 0; kc < 2; ++kc) {
        int r0 = q0 + l15;
        int r1 = min(r0 + 1, S_ - 1);
        v8s raw0 = *(const v8s*)&QH[base + (size_t)r0 * D_ + kc * 32 + quad * 8];
        v8s raw1 = *(const v8s*)&QH[base + (size_t)r1 * D_ + kc * 32 + quad * 8];
        #pragma unroll
        for (int j = 0; j < 8; ++j) {
            float ubj = ub[h * DH_ + kc * 32 + quad * 8 + j];
            float vbj = vb[h * DH_ + kc * 32 + quad * 8 + j];
            float f0 = bf2f((u16)raw0[j]);
            quf[kc][j]  = (short)f2bf(f0 + ubj);
            qvf0[kc][j] = (short)f2bf(f0 + vbj);
            qvf1[kc][j] = (short)f2bf(bf2f((u16)raw1[j]) + vbj);
        }
    }

    v4f o[4];
    float l_r[4];
    #pragma unroll
    for (int i = 0; i < 4; ++i) { o[i] = (v4f){0.f, 0.f, 0.f, 0.f}; l_r[i] = 0.f; }

    const int wb = l15 - quad * 4 + 15;   // wcol = ct*16 + wb - reg

    auto body = [&](int k0, const int phase) {
        // all waves finished reading the previous K/VT tile
        __syncthreads();

        // ---- cooperative stage of K and VT tiles (fire-and-forget DMA) ----
        #pragma unroll
        for (int c = 0; c < 2; ++c) {
            int seg = wave * 2 + c;
            CP16(KH + base + (size_t)(k0 + seg * 8 + lr8) * D_ + lc8, &Ks[seg * 512]);
            CP16(VT + vtb + (size_t)(seg * 8 + lr8) * S_ + k0 + lc8, &VTs[seg * 512]);
        }

        const int tmin = k0 - q0 - 15;
        const int jbase = (phase == 0) ? (S_ - 1 + tmin) : (tmin - 2);

        // PH fragment address for a given wcol-tile (phase folds at inline)
        auto phaddr = [&](int wcl) -> const u16* {
            int rw = wcl * 16 + l15;
            int j;
            if (phase == 1) {
                int t = tmin + rw;
                j = (t <= 0) ? (S_ - 1 + t) : max(t - 2, 0);
            } else {
                j = jbase + rw;
            }
            return &PH[base + (size_t)j * D_ + quad * 8];
        };

        // ---- pos pre-products: 1-deep pipelined PH loads + MFMA, one plane ----
        {
            const u16* ph0 = phaddr(0);
            v8s p0 = *(const v8s*)ph0;
            v8s p1 = *(const v8s*)(ph0 + 32);
            const bool doA = (tmin <= 0);
            #pragma unroll
            for (int wcl = 0; wcl < 5; ++wcl) {
                v8s n0, n1;
                if (wcl < 4) {                      // prefetch next tile's frags
                    const u16* phn = phaddr(wcl + 1);
                    n0 = *(const v8s*)phn;
                    n1 = *(const v8s*)(phn + 32);
                }
                int rw = wcl * 16 + l15;
                v4f sel;
                if (phase == 1) {
                    int t = tmin + rw;              // per-lane, shared by 4 regs
                    __builtin_amdgcn_s_setprio(1);
                    v4f a1 = (v4f){0.f, 0.f, 0.f, 0.f};
                    a1 = __builtin_amdgcn_mfma_f32_16x16x32_bf16(qvf1[0], p0, a1, 0, 0, 0);
                    a1 = __builtin_amdgcn_mfma_f32_16x16x32_bf16(qvf1[1], p1, a1, 0, 0, 0);
                    sel = a1;
                    if (doA) {
                        v4f a0 = (v4f){0.f, 0.f, 0.f, 0.f};
                        a0 = __builtin_amdgcn_mfma_f32_16x16x32_bf16(qvf0[0], p0, a0, 0, 0, 0);
                        a0 = __builtin_amdgcn_mfma_f32_16x16x32_bf16(qvf0[1], p1, a0, 0, 0, 0);
                        sel = (t >= 2) ? a1 : a0;   // per-lane cndmask
                    }
                    __builtin_amdgcn_s_setprio(0);
                } else {
                    const v8s a0s = (phase == 0) ? qvf0[0] : qvf1[0];
                    const v8s a1s = (phase == 0) ? qvf0[1] : qvf1[1];
                    __builtin_amdgcn_s_setprio(1);
                    v4f a = (v4f){0.f, 0.f, 0.f, 0.f};
                    a = __builtin_amdgcn_mfma_f32_16x16x32_bf16(a0s, p0, a, 0, 0, 0);
                    a = __builtin_amdgcn_mfma_f32_16x16x32_bf16(a1s, p1, a, 0, 0, 0);
                    __builtin_amdgcn_s_setprio(0);
                    sel = a;
                }
                ushort4 pw;
                pw.x = f2bf(sel[0]); pw.y = f2bf(sel[1]); pw.z = f2bf(sel[2]); pw.w = f2bf(sel[3]);
                *(ushort4*)&PmT[wave][rw][quad * 4] = pw;
                p0 = n0; p1 = n1;
            }
        }

        // staging complete & visible (syncthreads drains vmcnt+lgkmcnt)
        __syncthreads();

        // ---- content (K from LDS) + gather/exp per 16-col tile ----
        #pragma unroll
        for (int ct = 0; ct < 4; ++ct) {
            int kr = (ct * 16 + l15) * 64;
            v8s kbf0 = *(const v8s*)&Ks[kr + ((quad * 8) ^ ksw)];
            v8s kbf1 = *(const v8s*)&Ks[kr + ((32 + quad * 8) ^ ksw)];
            __builtin_amdgcn_s_setprio(1);
            v4f cs = (v4f){0.f, 0.f, 0.f, 0.f};
            cs = __builtin_amdgcn_mfma_f32_16x16x32_bf16(quf[0], kbf0, cs, 0, 0, 0);
            cs = __builtin_amdgcn_mfma_f32_16x16x32_bf16(quf[1], kbf1, cs, 0, 0, 0);
            __builtin_amdgcn_s_setprio(0);
            #pragma unroll
            for (int reg = 0; reg < 4; ++reg) {
                int qrow = quad * 4 + reg;
                int wcol = ct * 16 + wb - reg;
                float pos = bf2f(PmT[wave][wcol][qrow]);
                if (phase == 1) {
                    int t = tmin + wcol;
                    if (t == 1) pos = 0.f;
                }
                float e = __expf((cs[reg] + pos) * 0.03125f);
                ps[wave][qrow][ct * 16 + l15] = f2bf(e);
                l_r[reg] += e;
            }
        }

        // ---- PV (A-frags from ps, B-frags = VT from LDS) ----
        v8s af0 = *(const v8s*)&ps[wave][l15][quad * 8];
        v8s af1 = *(const v8s*)&ps[wave][l15][32 + quad * 8];
        __builtin_amdgcn_s_setprio(1);
        #pragma unroll
        for (int dt = 0; dt < 4; ++dt) {
            int vr = (dt * 16 + l15) * 64;
            v8s vbf0 = *(const v8s*)&VTs[vr + ((quad * 8) ^ ksw)];
            v8s vbf1 = *(const v8s*)&VTs[vr + ((32 + quad * 8) ^ ksw)];
            o[dt] = __builtin_amdgcn_mfma_f32_16x16x32_bf16(af0, vbf0, o[dt], 0, 0, 0);
            o[dt] = __builtin_amdgcn_mfma_f32_16x16x32_bf16(af1, vbf1, o[dt], 0, 0, 0);
        }
        __builtin_amdgcn_s_setprio(0);
    };

    // phase bounds: pure1 iff k0 <= q0-63; pure2 iff k0 >= q0+17
    const int k1end   = (q0 >= 63) ? ((((q0 - 63) >> 6) + 1) << 6) : 0;
    const int k2start = min((((q0 + 80) >> 6) << 6), S_);

    int k0 = 0;
    for (; k0 < k1end; k0 += 64)   body(k0, 0);
    for (; k0 < k2start; k0 += 64) body(k0, 1);
    for (; k0 < S_; k0 += 64)      body(k0, 2);

    // ---- row sums: in-quad shfl reduction (rows quad*4+reg live in this quad) ----
    #pragma unroll
    for (int reg = 0; reg < 4; ++reg) {
        float s = l_r[reg];
        #pragma unroll
        for (int off = 1; off < 16; off <<= 1)
            s += __shfl_xor(s, off, 16);
        l_r[reg] = 1.f / s;
    }
    #pragma unroll
    for (int dt = 0; dt < 4; ++dt)
        #pragma unroll
        for (int reg = 0; reg < 4; ++reg)
            AO[base + (size_t)(q0 + quad * 4 + reg) * D_ + dt * 16 + l15] =
                f2bf(o[dt][reg] * l_r[reg]);
}

extern "C" void kernel_launch(void* const* d_in, const int* in_sizes, int n_in,
                              void* d_out, int out_size, void* d_ws, size_t ws_size,
                              hipStream_t stream)
{
    (void)in_sizes; (void)n_in; (void)out_size; (void)ws_size;
    const float* q   = (const float*)d_in[0];
    const float* k   = (const float*)d_in[1];
    const float* v   = (const float*)d_in[2];
    const float* pe  = (const float*)d_in[3];
    const float* Wq  = (const float*)d_in[4];
    const float* bq  = (const float*)d_in[5];
    const float* Wk  = (const float*)d_in[6];
    const float* bk  = (const float*)d_in[7];
    const float* Wv  = (const float*)d_in[8];
    const float* bv  = (const float*)d_in[9];
    const float* Wp  = (const float*)d_in[10];
    const float* ub  = (const float*)d_in[11];
    const float* vbs = (const float*)d_in[12];
    const float* Wo  = (const float*)d_in[13];
    const float* bo  = (const float*)d_in[14];
    float* out = (float*)d_out;

    const size_t NSD = (size_t)B_ * S_ * D_;   // 4,194,304
    const size_t DD  = (size_t)D_ * D_;
    u16* ws = (u16*)d_ws;
    u16* qB  = ws;
    u16* kB  = qB + NSD;
    u16* vB  = kB + NSD;
    u16* pB  = vB + NSD;
    u16* WqB = pB + NSD;
    u16* WkB = WqB + DD;
    u16* WvB = WkB + DD;
    u16* WpB = WvB + DD;
    u16* WoB = WpB + DD;
    u16* QH  = WoB + DD;
    u16* KH  = QH + NSD;
    u16* VT  = KH + NSD;           // V projection written transposed
    u16* PHb = VT + NSD;
    u16* AO  = qB;                 // alias: qB dead after gemm_proj

    const int M = B_ * S_;         // 4096

    cvt9<<<dim3((int)(NSD / 4 / 256), 9), 256, 0, stream>>>(
        q, k, v, pe, Wq, Wk, Wv, Wp, Wo,
        qB, kB, vB, pB, WqB, WkB, WvB, WpB, WoB,
        (int)(NSD / 4), (int)(DD / 4));

    gemm_proj<<<dim3(D_ / 128, M / 128, 4), 256, 0, stream>>>(
        qB, kB, vB, pB, WqB, WkB, WvB, WpB, bq, bk, bv, QH, KH, VT, PHb);

    rel_attn16<<<dim3(S_ / 64, B_ * H_), 256, 0, stream>>>(QH, KH, VT, PHb, ub, vbs, AO);

    gemm_out<<<dim3(D_ / 128, M / 64), 256, 0, stream>>>(AO, WoB, bo, out);
}